// Round 1
// baseline (266.358 us; speedup 1.0000x reference)
//
#include <hip/hip_runtime.h>

#define NTOK 3072
#define DM   1280
#define NH   16
#define HD   80
#define HDP  96
#define NSEG 8
#define QKVC 3840

typedef __attribute__((ext_vector_type(4))) float  f32x4;
typedef __attribute__((ext_vector_type(8))) __bf16 bf16x8;
typedef __attribute__((ext_vector_type(8))) unsigned short ushort8;
typedef __attribute__((ext_vector_type(4))) unsigned short ushort4v;

static __device__ __forceinline__ unsigned short f2bf(float f){
  union{float f; unsigned int u;} v; v.f=f;
  unsigned int r = v.u + 0x7fffu + ((v.u>>16)&1u);
  return (unsigned short)(r>>16);
}
static __device__ __forceinline__ float bf2f(unsigned short u){
  union{unsigned int i; float f;} v; v.i = ((unsigned int)u)<<16; return v.f;
}
static __device__ __forceinline__ void gload_lds16(const void* g, void* l){
  __builtin_amdgcn_global_load_lds((const __attribute__((address_space(1))) void*)g,
                                   (__attribute__((address_space(3))) void*)l, 16, 0, 0);
}

// ---------------- elementwise cast f32 -> bf16 ----------------
__global__ void cast_f32_bf16(const float* __restrict__ src, unsigned short* __restrict__ dst, int n){
  int i = (blockIdx.x*256 + threadIdx.x)*4;
  if (i >= n) return;
  f32x4 v = *reinterpret_cast<const f32x4*>(&src[i]);
  ushort4v o;
  o[0]=f2bf(v[0]); o[1]=f2bf(v[1]); o[2]=f2bf(v[2]); o[3]=f2bf(v[3]);
  *reinterpret_cast<ushort4v*>(&dst[i]) = o;
}

// ---------------- tiled transpose + cast: src[R][C] f32 -> dst[C][R] bf16 ----------------
__global__ void transpose_cast(const float* __restrict__ src, unsigned short* __restrict__ dst, int R, int C){
  __shared__ unsigned short tile[32][33];
  int c0 = blockIdx.x*32, r0 = blockIdx.y*32;
  int tx = threadIdx.x, ty = threadIdx.y;   // 32 x 8
  #pragma unroll
  for (int i=0;i<4;i++){
    int r = r0 + ty + i*8;
    tile[ty+i*8][tx] = f2bf(src[(size_t)r*C + c0 + tx]);
  }
  __syncthreads();
  #pragma unroll
  for (int i=0;i<4;i++){
    int c = c0 + ty + i*8;
    dst[(size_t)c*R + r0 + tx] = tile[tx][ty+i*8];
  }
}

// ---------------- m97-style bf16 GEMM: C = A[M][Kd] * Bt[Ncol][Kd]^T + bias ----------------
template<int OUT_BF16>
__global__ __launch_bounds__(256) void gemm_bt(
    const unsigned short* __restrict__ A,
    const unsigned short* __restrict__ Bt,
    const float* __restrict__ bias,
    unsigned short* __restrict__ Cb,
    float* __restrict__ Cf,
    int M, int Ncol, int Kd)
{
  __shared__ unsigned short As[128*32];
  __shared__ unsigned short Bs[128*32];
  const int tid  = threadIdx.x;
  const int lane = tid & 63, wave = tid >> 6;
  const int wr = wave >> 1, wc = wave & 1;
  const int bm = blockIdx.y, bn = blockIdx.x;
  const f32x4 vzero = {0.f,0.f,0.f,0.f};

  f32x4 acc[4][4];
  #pragma unroll
  for (int i=0;i<4;i++)
    #pragma unroll
    for (int j=0;j<4;j++) acc[i][j] = vzero;

  const int rsub = lane>>2;          // 0..15
  const int kc   = (lane&3)*8;       // 0,8,16,24
  const unsigned short* Ab = A  + (size_t)(bm*128 + wave*32 + rsub)*Kd + kc;
  const unsigned short* Bb = Bt + (size_t)(bn*128 + wave*32 + rsub)*Kd + kc;

  for (int k0=0; k0<Kd; k0+=32){
    __syncthreads();
    #pragma unroll
    for (int i=0;i<2;i++){
      gload_lds16(Ab + (size_t)i*16*Kd + k0, &As[(wave*2+i)*512]);
      gload_lds16(Bb + (size_t)i*16*Kd + k0, &Bs[(wave*2+i)*512]);
    }
    __syncthreads();
    bf16x8 a[4], b[4];
    #pragma unroll
    for (int mf=0; mf<4; mf++)
      a[mf] = *reinterpret_cast<const bf16x8*>(&As[(wr*64 + mf*16 + (lane&15))*32 + ((lane>>4)<<3)]);
    #pragma unroll
    for (int nf=0; nf<4; nf++)
      b[nf] = *reinterpret_cast<const bf16x8*>(&Bs[(wc*64 + nf*16 + (lane&15))*32 + ((lane>>4)<<3)]);
    #pragma unroll
    for (int mf=0; mf<4; mf++)
      #pragma unroll
      for (int nf=0; nf<4; nf++)
        acc[mf][nf] = __builtin_amdgcn_mfma_f32_16x16x32_bf16(a[mf], b[nf], acc[mf][nf], 0,0,0);
  }

  const int crow0 = bm*128 + wr*64;
  const int ccol0 = bn*128 + wc*64;
  #pragma unroll
  for (int nf=0; nf<4; nf++){
    int col = ccol0 + nf*16 + (lane&15);
    float bv = bias[col];
    #pragma unroll
    for (int mf=0; mf<4; mf++){
      #pragma unroll
      for (int r=0;r<4;r++){
        int row = crow0 + mf*16 + ((lane>>4)<<2) + r;
        float v = acc[mf][nf][r] + bv;
        if (OUT_BF16) Cb[(size_t)row*Ncol + col] = f2bf(v);
        else          Cf[(size_t)row*Ncol + col] = v;
      }
    }
  }
}

// ---------------- RoPE + repack to [H][N][96] (pad 80->96 with zeros) ----------------
__global__ void rope_repack(const unsigned short* __restrict__ qkv,
                            const float* __restrict__ cosNK, const float* __restrict__ sinNK,
                            unsigned short* __restrict__ Qr, unsigned short* __restrict__ Kr)
{
  int idx = blockIdx.x*256 + threadIdx.x;
  int k  = idx % HDP;
  int nh = idx / HDP;
  int n  = nh % NTOK;
  int h  = nh / NTOK;
  size_t dsti = (size_t)(h*NTOK + n)*HDP + k;
  if (k >= HD){ Qr[dsti]=0; Kr[dsti]=0; return; }
  float c = cosNK[n*HD + k], s = sinNK[n*HD + k];
  int   kp  = (k < 40) ? (k+40) : (k-40);
  float sgn = (k < 40) ? -1.f : 1.f;
  size_t base = (size_t)n*QKVC + h*HD;
  float q   = bf2f(qkv[base + k]);
  float qp  = bf2f(qkv[base + kp]);
  float kk  = bf2f(qkv[base + DM + k]);
  float kkp = bf2f(qkv[base + DM + kp]);
  Qr[dsti] = f2bf(q*c  + sgn*qp*s);
  Kr[dsti] = f2bf(kk*c + sgn*kkp*s);
}

// ---------------- segment-masked flash attention ----------------
__global__ __launch_bounds__(256) void attn_kernel(
    const unsigned short* __restrict__ Qr,
    const unsigned short* __restrict__ Kr,
    const unsigned short* __restrict__ qkv,
    const int* __restrict__ cu,
    unsigned short* __restrict__ attn_out)
{
  __shared__ unsigned short Qs[64*HDP];
  __shared__ unsigned short Ks[64*HDP];
  __shared__ unsigned short Vst[HDP*64];   // [col 0..95][krow 0..63]
  __shared__ unsigned short Ps[64*64];
  __shared__ int rs[64], re[64];

  const int h   = blockIdx.y;
  const int q0  = blockIdx.x*64;
  const int tid = threadIdx.x;
  const int lane = tid & 63;
  const int wave = tid >> 6;
  const f32x4 vzero = {0.f,0.f,0.f,0.f};

  if (tid < 64){
    int row = q0 + tid;
    int seg = 0;
    #pragma unroll
    for (int j=1;j<NSEG;j++) seg += (cu[j] <= row) ? 1 : 0;
    rs[tid] = cu[seg];
    re[tid] = cu[seg+1];
  }
  { // stage Q tile
    const unsigned short* src = Qr + ((size_t)h*NTOK + q0)*HDP;
    #pragma unroll
    for (int i=0;i<3;i++){
      int off = i*2048 + tid*8;
      *reinterpret_cast<ushort8*>(&Qs[off]) = *reinterpret_cast<const ushort8*>(&src[off]);
    }
  }
  __syncthreads();
  int kmin = NTOK, kmax = 0;
  for (int j=0;j<64;j++){
    int a = rs[j]; if (a < kmin) kmin = a;
    int b = re[j]; if (b > kmax) kmax = b;
  }

  f32x4 accO[6];
  #pragma unroll
  for (int i=0;i<6;i++) accO[i] = vzero;
  float m_r[4] = {-1e30f,-1e30f,-1e30f,-1e30f};
  float l_r[4] = {0.f,0.f,0.f,0.f};
  const int row_lds0 = wave*16 + ((lane>>4)<<2);

  for (int kt = (kmin/64)*64; kt < kmax; kt += 64){
    __syncthreads();
    { // stage K tile
      const unsigned short* src = Kr + ((size_t)h*NTOK + kt)*HDP;
      #pragma unroll
      for (int i=0;i<3;i++){
        int off = i*2048 + tid*8;
        *reinterpret_cast<ushort8*>(&Ks[off]) = *reinterpret_cast<const ushort8*>(&src[off]);
      }
    }
    // stage V transposed from qkv buffer
    if (tid < 128){
      int r = tid >> 1, cb = (tid & 1)*40;
      const unsigned short* src = qkv + (size_t)(kt + r)*QKVC + 2*DM + h*HD + cb;
      #pragma unroll
      for (int jj=0;jj<5;jj++){
        ushort8 v = *reinterpret_cast<const ushort8*>(&src[jj*8]);
        #pragma unroll
        for (int e=0;e<8;e++) Vst[(cb + jj*8 + e)*64 + r] = v[e];
      }
    } else {
      int t2 = tid - 128;
      #pragma unroll
      for (int e=0;e<8;e++) Vst[80*64 + t2*8 + e] = 0;
    }
    __syncthreads();

    // S = Q K^T : wave computes rows wave*16..+15, cols 0..63
    f32x4 accS[4];
    #pragma unroll
    for (int i=0;i<4;i++) accS[i] = vzero;
    #pragma unroll
    for (int ks=0; ks<3; ks++){
      bf16x8 aq = *reinterpret_cast<const bf16x8*>(&Qs[(wave*16 + (lane&15))*HDP + ks*32 + ((lane>>4)<<3)]);
      #pragma unroll
      for (int nf=0;nf<4;nf++){
        bf16x8 bk = *reinterpret_cast<const bf16x8*>(&Ks[(nf*16 + (lane&15))*HDP + ks*32 + ((lane>>4)<<3)]);
        accS[nf] = __builtin_amdgcn_mfma_f32_16x16x32_bf16(aq, bk, accS[nf], 0,0,0);
      }
    }
    const float scale = 0.11180339887498948f;  // 1/sqrt(80)
    #pragma unroll
    for (int r=0;r<4;r++){
      int row_i = row_lds0 + r;
      int rst = rs[row_i], ren = re[row_i];
      float sv[4]; bool ok[4];
      float mx = -1e30f;
      #pragma unroll
      for (int nf=0;nf<4;nf++){
        int kcol = kt + nf*16 + (lane&15);
        ok[nf] = (kcol >= rst) && (kcol < ren);
        sv[nf] = accS[nf][r]*scale;
        if (ok[nf]) mx = fmaxf(mx, sv[nf]);
      }
      #pragma unroll
      for (int d=1; d<16; d<<=1) mx = fmaxf(mx, __shfl_xor(mx, d, 64));
      float mnew  = fmaxf(m_r[r], mx);
      float alpha = __expf(m_r[r] - mnew);
      m_r[r] = mnew;
      float lsum = 0.f;
      #pragma unroll
      for (int nf=0;nf<4;nf++){
        float p = ok[nf] ? __expf(sv[nf] - mnew) : 0.f;
        Ps[row_i*64 + nf*16 + (lane&15)] = f2bf(p);
        lsum += p;
      }
      #pragma unroll
      for (int d=1; d<16; d<<=1) lsum += __shfl_xor(lsum, d, 64);
      l_r[r] = l_r[r]*alpha + lsum;
      #pragma unroll
      for (int cf=0; cf<6; cf++) accO[cf][r] *= alpha;
    }
    // O += P @ V
    #pragma unroll
    for (int ks=0; ks<2; ks++){
      bf16x8 ap = *reinterpret_cast<const bf16x8*>(&Ps[(wave*16 + (lane&15))*64 + ks*32 + ((lane>>4)<<3)]);
      #pragma unroll
      for (int cf=0; cf<6; cf++){
        bf16x8 bv = *reinterpret_cast<const bf16x8*>(&Vst[(cf*16 + (lane&15))*64 + ks*32 + ((lane>>4)<<3)]);
        accO[cf] = __builtin_amdgcn_mfma_f32_16x16x32_bf16(ap, bv, accO[cf], 0,0,0);
      }
    }
  }

  // epilogue: write attn[N][1280] (cols >= 80 in padded head dim are dropped)
  #pragma unroll
  for (int cf=0; cf<5; cf++){
    #pragma unroll
    for (int r=0;r<4;r++){
      int row = q0 + row_lds0 + r;
      int col = h*HD + cf*16 + (lane&15);
      float o = accO[cf][r] / l_r[r];
      attn_out[(size_t)row*DM + col] = f2bf(o);
    }
  }
}

extern "C" void kernel_launch(void* const* d_in, const int* in_sizes, int n_in,
                              void* d_out, int out_size, void* d_ws, size_t ws_size,
                              hipStream_t stream)
{
  const float* hidden = (const float*)d_in[0];
  const int*   cu     = (const int*)  d_in[1];
  const float* cosNK  = (const float*)d_in[2];
  const float* sinNK  = (const float*)d_in[3];
  const float* qkv_w  = (const float*)d_in[4];
  const float* qkv_b  = (const float*)d_in[5];
  const float* proj_w = (const float*)d_in[6];
  const float* proj_b = (const float*)d_in[7];
  float* out = (float*)d_out;

  char* w = (char*)d_ws;
  unsigned short* hid_bf  = (unsigned short*)w;  w += (size_t)NTOK*DM*2;
  unsigned short* qkvwT   = (unsigned short*)w;  w += (size_t)QKVC*DM*2;
  unsigned short* projwT  = (unsigned short*)w;  w += (size_t)DM*DM*2;
  unsigned short* qkv_bf  = (unsigned short*)w;  w += (size_t)NTOK*QKVC*2;
  unsigned short* Qr      = (unsigned short*)w;  w += (size_t)NH*NTOK*HDP*2;
  unsigned short* Kr      = (unsigned short*)w;  w += (size_t)NH*NTOK*HDP*2;
  unsigned short* attn_bf = (unsigned short*)w;  w += (size_t)NTOK*DM*2;

  cast_f32_bf16<<<(NTOK*DM/4 + 255)/256, 256, 0, stream>>>(hidden, hid_bf, NTOK*DM);
  transpose_cast<<<dim3(QKVC/32, DM/32), dim3(32,8), 0, stream>>>(qkv_w, qkvwT, DM, QKVC);
  transpose_cast<<<dim3(DM/32,  DM/32), dim3(32,8), 0, stream>>>(proj_w, projwT, DM, DM);
  gemm_bt<1><<<dim3(QKVC/128, NTOK/128), 256, 0, stream>>>(hid_bf, qkvwT, qkv_b, qkv_bf, nullptr, NTOK, QKVC, DM);
  rope_repack<<<(NH*NTOK*HDP)/256, 256, 0, stream>>>(qkv_bf, cosNK, sinNK, Qr, Kr);
  attn_kernel<<<dim3(NTOK/64, NH), 256, 0, stream>>>(Qr, Kr, qkv_bf, cu, attn_bf);
  gemm_bt<0><<<dim3(DM/128, NTOK/128), 256, 0, stream>>>(attn_bf, projwT, proj_b, nullptr, out, NTOK, DM, DM);
}